// Round 11
// baseline (78.991 us; speedup 1.0000x reference)
//
#include <hip/hip_runtime.h>
#include <hip/hip_bf16.h>

typedef __attribute__((ext_vector_type(8))) short bf16x8;
typedef __attribute__((ext_vector_type(4))) short s16x4;
typedef __attribute__((ext_vector_type(4))) float f32x4;

#define B_ 64
#define T_ 1024
#define N_ 512

#define VMWAIT(N) asm volatile("s_waitcnt vmcnt(" #N ")" ::: "memory")
#define LGKM0()   asm volatile("s_waitcnt lgkmcnt(0)" ::: "memory")

__device__ __forceinline__ void async16(const void* g, void* l) {
  __builtin_amdgcn_global_load_lds(
      (const __attribute__((address_space(1))) unsigned int*)g,
      (__attribute__((address_space(3))) unsigned int*)l, 16, 0, 0);
}

__device__ __forceinline__ short f2bf(float f) {
  return __builtin_bit_cast(short, __float2bfloat16(f));
}
__device__ __forceinline__ float bf2f(short s) {
  return __builtin_bit_cast(float, ((unsigned)(unsigned short)s) << 16);
}

// K1 (unchanged, ~92% of BW floor): transpose fp32 (T,N) -> bf16 (N,T) + stats.
__global__ __launch_bounds__(256, 4) void k_prep(
    const float* __restrict__ X, short* __restrict__ XbT,
    float* __restrict__ amu, float* __restrict__ invd)
{
  __shared__ __align__(16) short tile[64][68];
  const int b   = blockIdx.y;
  const int n0  = blockIdx.x * 64;
  const int tid = threadIdx.x;
  const int nch = tid & 15;
  const int rg  = tid >> 4;

  float s[4] = {0.f,0.f,0.f,0.f}, q[4] = {0.f,0.f,0.f,0.f};

  for (int tt = 0; tt < 16; ++tt) {
    const int t0 = tt * 64;
    #pragma unroll
    for (int i = 0; i < 4; ++i) {
      const int tr = rg + i * 16;
      const float4 v = *(const float4*)&X[((size_t)b*T_ + t0 + tr)*N_ + n0 + nch*4];
      short bb[4];
      bb[0] = f2bf(v.x); bb[1] = f2bf(v.y); bb[2] = f2bf(v.z); bb[3] = f2bf(v.w);
      #pragma unroll
      for (int c = 0; c < 4; ++c) { float f = bf2f(bb[c]); s[c] += f; q[c] += f*f; }
      s16x4 pk = { bb[0], bb[1], bb[2], bb[3] };
      *(s16x4*)&tile[tr][nch*4] = pk;
    }
    __syncthreads();
    #pragma unroll
    for (int i = 0; i < 4; ++i) {
      const int n = rg + i * 16;
      s16x4 o = { tile[nch*4+0][n], tile[nch*4+1][n],
                  tile[nch*4+2][n], tile[nch*4+3][n] };
      *(s16x4*)&XbT[((size_t)b*N_ + n0 + n)*T_ + t0 + nch*4] = o;
    }
    __syncthreads();
  }

  float* fb = (float*)&tile[0][0];
  #pragma unroll
  for (int c = 0; c < 4; ++c) { fb[tid*8 + c] = s[c]; fb[tid*8 + 4 + c] = q[c]; }
  __syncthreads();
  if (tid < 64) {
    const int qc = tid >> 2, c = tid & 3;
    float cs = 0.f, sq = 0.f;
    #pragma unroll
    for (int g = 0; g < 16; ++g) {
      cs += fb[(g*16 + qc)*8 + c];
      sq += fb[(g*16 + qc)*8 + 4 + c];
    }
    const int n = n0 + qc*4 + c;
    amu[b*N_ + n]  = cs * (1.f/32.f);
    invd[b*N_ + n] = rsqrtf(fmaxf(sq - cs*cs*(1.f/1024.f), 1e-20f));
  }
}

// Barrier-free per-wave gram pipeline. Wave-private LDS region (16 KB):
// buf in {0,1} at +buf*4096 shorts; A slot [64][32] at +0, B at +2048.
// LPW = global_load_lds per wave per tile (8 normal, 4 when A==B slot).
// Step t: vmcnt(LPW) certifies tile t landed (per-wave counter, 2-deep);
// ds_read frags(t); lgkmcnt(0) = WAR guard; restage buf with tile t+2; MFMA.
template<int LPW>
__device__ __forceinline__ void wave_pipeline(
    const short* __restrict__ Xb, const size_t* gA, const size_t* gB,
    short* ldsW, int lane, int aoffL, int boffL, f32x4 (&acc)[4][4])
{
  auto stg = [&](int buf, int kb) {
    char* base = (char*)ldsW + buf * 8192;
    #pragma unroll
    for (int m = 0; m < 4; ++m)
      async16(Xb + gA[m] + kb, base + m * 1024 + lane * 16);
    if constexpr (LPW == 8) {
      #pragma unroll
      for (int m = 0; m < 4; ++m)
        async16(Xb + gB[m] + kb, base + 4096 + m * 1024 + lane * 16);
    }
  };
  auto body = [&](int buf, int kb_next, bool do_stg) {
    const short* P = ldsW + buf * 4096;
    bf16x8 af[4], bfv[4];
    #pragma unroll
    for (int mi = 0; mi < 4; ++mi) af[mi] = *(const bf16x8*)&P[aoffL + mi * 512];
    #pragma unroll
    for (int ni = 0; ni < 4; ++ni) bfv[ni] = *(const bf16x8*)&P[boffL + ni * 512];
    LGKM0();                                   // frags in regs; buf reusable
    if (do_stg) stg(buf, kb_next);
    __builtin_amdgcn_s_setprio(1);
    #pragma unroll
    for (int mi = 0; mi < 4; ++mi)
      #pragma unroll
      for (int ni = 0; ni < 4; ++ni)
        acc[mi][ni] = __builtin_amdgcn_mfma_f32_16x16x32_bf16(
            af[mi], bfv[ni], acc[mi][ni], 0, 0, 0);
    __builtin_amdgcn_s_setprio(0);
  };

  stg(0, 0); stg(1, 32);                       // tiles 0,1 in flight
  #pragma unroll 1
  for (int t = 0; t < 30; t += 2) {
    if constexpr (LPW == 8) VMWAIT(8); else VMWAIT(4);
    body(0, (t + 2) * 32, true);
    if constexpr (LPW == 8) VMWAIT(8); else VMWAIT(4);
    body(1, (t + 3) * 32, true);
  }
  if constexpr (LPW == 8) VMWAIT(8); else VMWAIT(4);
  body(0, 0, false);                           // t=30
  VMWAIT(0);
  body(1, 0, false);                           // t=31
}

// K2: per-batch symmetric Gram, 10 upper-tri 128x128 tiles/batch, 640 blocks.
// NO block barriers in the K-loop: each wave stages/consumes privately.
__global__ __launch_bounds__(256, 2) void k_gram(
    const short* __restrict__ XbT, const float* __restrict__ amu,
    const float* __restrict__ invd, float* __restrict__ out)
{
  __shared__ __align__(16) short lds[4][8192];   // 16 KB per wave, 64 KB

  const int bid = (blockIdx.x & 7) * 80 + (blockIdx.x >> 3);  // 8 XCD x 80
  const int b = bid / 10;
  const int t = bid - b * 10;
  const int ip = (t >= 4) + (t >= 7) + (t >= 9);
  const int jp = ip + t - ((ip * (9 - ip)) >> 1);
  const int rowBase = ip * 128, colBase = jp * 128;
  const bool diag = (ip == jp);

  const int tid = threadIdx.x, lane = tid & 63, wave = tid >> 6;
  const int wr = wave >> 1, wc = wave & 1;
  const short* Xb = XbT + (size_t)b * N_ * T_;

  const int rowG = rowBase + wr * 64;          // this wave's A rows
  const int colG = colBase + wc * 64;          // this wave's B rows
  const bool dup = diag && (wr == wc);         // A==B slot: stage once

  // per-lane global sources for the 4 staging chunks of each 64x32 slot:
  // chunk q = 64m + lane -> row = q>>2, cc = q&3; source k-chunk
  // cg = cc ^ ((row>>1)&3)  (inverse of the fragment-read swizzle).
  size_t gA[4], gB[4];
  #pragma unroll
  for (int m = 0; m < 4; ++m) {
    const int row = 16 * m + (lane >> 2);
    const int cg  = (lane & 3) ^ ((row >> 1) & 3);
    gA[m] = (size_t)(rowG + row) * T_ + cg * 8;
    gB[m] = (size_t)(colG + row) * T_ + cg * 8;
  }

  const int fr = lane & 15, kc = lane >> 4;
  const int swz   = (kc ^ ((fr >> 1) & 3)) * 8;
  const int aoffL = fr * 32 + swz;
  const int boffL = (dup ? 0 : 2048) + fr * 32 + swz;

  f32x4 acc[4][4] = {};
  if (dup) wave_pipeline<4>(Xb, gA, gB, &lds[wave][0], lane, aoffL, boffL, acc);
  else     wave_pipeline<8>(Xb, gA, gB, &lds[wave][0], lane, aoffL, boffL, acc);

  // Epilogue (identical to r4). C/D map: col = lane&15, row = (lane>>4)*4+reg.
  const int jc = colBase + wc * 64 + fr;
  float aj[4], dj[4];
  #pragma unroll
  for (int ni = 0; ni < 4; ++ni) {
    aj[ni] = amu [b*N_ + jc + ni*16];
    dj[ni] = invd[b*N_ + jc + ni*16];
  }
  #pragma unroll
  for (int mi = 0; mi < 4; ++mi) {
    const int ibase = rowBase + wr*64 + mi*16 + kc*4;
    float ai[4], di[4];
    #pragma unroll
    for (int r = 0; r < 4; ++r) {
      ai[r] = amu [b*N_ + ibase + r];
      di[r] = invd[b*N_ + ibase + r];
    }
    #pragma unroll
    for (int ni = 0; ni < 4; ++ni) {
      f32x4 g;
      #pragma unroll
      for (int r = 0; r < 4; ++r) {
        float v = (acc[mi][ni][r] - ai[r]*aj[ni]) * (di[r]*dj[ni]);
        g[r] = fminf(fmaxf(v, -1.f), 1.f);
      }
      const int J = jc + ni * 16;
      #pragma unroll
      for (int r = 0; r < 4; ++r)
        out[((size_t)b*N_ + ibase + r)*N_ + J] = g[r];       // tile (ip,jp)
      if (!diag)
        *(f32x4*)&out[((size_t)b*N_ + J)*N_ + ibase] = g;    // mirror (jp,ip)
    }
  }
}

extern "C" void kernel_launch(void* const* d_in, const int* in_sizes, int n_in,
                              void* d_out, int out_size, void* d_ws, size_t ws_size,
                              hipStream_t stream) {
  const float* X = (const float*)d_in[0];
  // bn_weight / bn_bias provably cancel in the correlation output.
  float* out = (float*)d_out;

  char* ws = (char*)d_ws;
  short* XbT  = (short*)ws;                      // 64 MiB bf16 (N,T)
  size_t off  = (size_t)B_ * N_ * T_ * sizeof(short);
  float* amu  = (float*)(ws + off);              // 128 KiB
  float* invd = amu + B_ * N_;                   // 128 KiB

  k_prep<<<dim3(N_/64, B_), 256, 0, stream>>>(X, XbT, amu, invd);
  k_gram<<<dim3(64 * 10), 256, 0, stream>>>(XbT, amu, invd, out);
}

// Round 12
// 71.202 us; speedup vs baseline: 1.1094x; 1.1094x over previous
//
#include <hip/hip_runtime.h>
#include <hip/hip_bf16.h>

typedef __attribute__((ext_vector_type(8))) short bf16x8;
typedef __attribute__((ext_vector_type(4))) short s16x4;
typedef __attribute__((ext_vector_type(4))) float f32x4;

#define B_ 64
#define T_ 1024
#define N_ 512

#define FENCE() asm volatile("" ::: "memory")
#define VMWAIT(N) asm volatile("s_waitcnt vmcnt(" #N ")" ::: "memory")
#define LGKM0()  asm volatile("s_waitcnt lgkmcnt(0)" ::: "memory")
#define BAR() __builtin_amdgcn_s_barrier()

__device__ __forceinline__ void async16(const void* g, void* l) {
  __builtin_amdgcn_global_load_lds(
      (const __attribute__((address_space(1))) unsigned int*)g,
      (__attribute__((address_space(3))) unsigned int*)l, 16, 0, 0);
}

__device__ __forceinline__ short f2bf(float f) {
  return __builtin_bit_cast(short, __float2bfloat16(f));
}
__device__ __forceinline__ float bf2f(short s) {
  return __builtin_bit_cast(float, ((unsigned)(unsigned short)s) << 16);
}

// K1 v2: latency-tuned transpose. 1024 blocks (32-col n-strips x 64 b), full
// T per block (stats atomics-free). LGKM-only raw barriers (deps are LDS-only;
// global loads/stores fly across). 1-deep register prefetch of next iter.
__global__ __launch_bounds__(256, 4) void k_prep(
    const float* __restrict__ X, short* __restrict__ XbT,
    float* __restrict__ amu, float* __restrict__ invd)
{
  __shared__ __align__(16) char smraw[8192];       // tile 4.6KB / fb 8KB
  short (*tile)[36] = (short(*)[36])smraw;

  const int b   = blockIdx.y;
  const int n0  = blockIdx.x * 32;
  const int tid = threadIdx.x;
  const int nch = tid & 7,  rg = tid >> 3;         // load map: 2 rows/thread
  const int sch = tid & 15, sn = tid >> 4;         // store map

  float s[4] = {0.f,0.f,0.f,0.f}, q[4] = {0.f,0.f,0.f,0.f};
  const float* base0 = X + (size_t)b * T_ * N_ + n0 + nch * 4;

  float4 vA0, vA1, vB0, vB1;

  #define LOADI(u0, u1, tt) do {                                        \
    const float* p_ = base0 + (size_t)((tt) * 64 + rg) * N_;            \
    u0 = *(const float4*)p_;                                            \
    u1 = *(const float4*)(p_ + (size_t)32 * N_);                        \
  } while (0)

  #define WRITEI(u0, u1) do {                                           \
    const float4* uu_[2] = { &u0, &u1 };                                \
    _Pragma("unroll")                                                   \
    for (int i = 0; i < 2; ++i) {                                       \
      const float4 u = *uu_[i];                                         \
      short b0 = f2bf(u.x), b1 = f2bf(u.y), b2 = f2bf(u.z), b3 = f2bf(u.w); \
      float f0 = bf2f(b0), f1 = bf2f(b1), f2 = bf2f(b2), f3 = bf2f(b3); \
      s[0] += f0; q[0] += f0*f0;  s[1] += f1; q[1] += f1*f1;            \
      s[2] += f2; q[2] += f2*f2;  s[3] += f3; q[3] += f3*f3;            \
      s16x4 pk = { b0, b1, b2, b3 };                                    \
      *(s16x4*)&tile[rg + i * 32][nch * 4] = pk;                        \
    }                                                                   \
  } while (0)

  #define STOREI(tt) do {                                               \
    _Pragma("unroll")                                                   \
    for (int i = 0; i < 2; ++i) {                                       \
      const int n_ = sn + i * 16;                                       \
      s16x4 o = { tile[sch*4+0][n_], tile[sch*4+1][n_],                 \
                  tile[sch*4+2][n_], tile[sch*4+3][n_] };               \
      *(s16x4*)&XbT[((size_t)b*N_ + n0 + n_)*T_ + (tt)*64 + sch*4] = o; \
    }                                                                   \
  } while (0)

  LOADI(vA0, vA1, 0);
  #pragma unroll 1
  for (int tt = 0; tt < 16; tt += 2) {
    WRITEI(vA0, vA1);                    // implicit vmcnt wait on vA here
    if (tt + 1 < 16) LOADI(vB0, vB1, tt + 1);   // issue early
    LGKM0(); BAR(); FENCE();             // publish tile; vmem NOT drained
    STOREI(tt);                          // ds_read + global_store
    LGKM0(); BAR(); FENCE();             // reads sealed; tile reusable

    WRITEI(vB0, vB1);
    if (tt + 2 < 16) LOADI(vA0, vA1, tt + 2);
    LGKM0(); BAR(); FENCE();
    STOREI(tt + 1);
    LGKM0(); BAR(); FENCE();
  }

  // stats block-reduce (reuse smraw as fp32 scratch; tile fully consumed)
  __syncthreads();
  float* fb = (float*)smraw;
  #pragma unroll
  for (int c = 0; c < 4; ++c) { fb[tid*8 + c] = s[c]; fb[tid*8 + 4 + c] = q[c]; }
  __syncthreads();
  if (tid < 32) {
    const int nc = tid >> 2, c = tid & 3;
    float cs = 0.f, sq = 0.f;
    #pragma unroll 1
    for (int r = 0; r < 32; ++r) {
      cs += fb[(r*8 + nc)*8 + c];
      sq += fb[(r*8 + nc)*8 + 4 + c];
    }
    const int n = n0 + nc*4 + c;
    amu[b*N_ + n]  = cs * (1.f/32.f);                                // /sqrt(T)
    invd[b*N_ + n] = rsqrtf(fmaxf(sq - cs*cs*(1.f/1024.f), 1e-20f)); // rsqrt(Gii)
  }
  #undef LOADI
  #undef WRITEI
  #undef STOREI
}

// ---- K2: r4 VERBATIM (best measured: 68.2 total) ----
__device__ __forceinline__ void compute_step(
    const short* A, const short* Bm, int aoff, int boff, int swz,
    f32x4 (&acc)[4][4])
{
  bf16x8 af[4], bfv[4];
  #pragma unroll
  for (int mi = 0; mi < 4; ++mi) af[mi] = *(const bf16x8*)&A[aoff + mi*512 + swz];
  #pragma unroll
  for (int ni = 0; ni < 4; ++ni) bfv[ni] = *(const bf16x8*)&Bm[boff + ni*512 + swz];
  #pragma unroll
  for (int mi = 0; mi < 4; ++mi)
    #pragma unroll
    for (int ni = 0; ni < 4; ++ni)
      acc[mi][ni] = __builtin_amdgcn_mfma_f32_16x16x32_bf16(
          af[mi], bfv[ni], acc[mi][ni], 0, 0, 0);
}

template<bool DIAG>
__device__ __forceinline__ void gram_main(
    const short* __restrict__ Xb,
    size_t ga0, size_t ga1, size_t gb0, size_t gb1,
    short (*ldsA)[4096], short (*ldsB)[4096],
    int tid, int aoff, int boff, int swz, f32x4 (&acc)[4][4])
{
  auto stg = [&](int bi, int kb) {
    char* la_ = (char*)ldsA[bi];
    async16(Xb + ga0 + kb, la_ + tid*16);
    async16(Xb + ga1 + kb, la_ + (tid+256)*16);
    if (!DIAG) {
      char* lb_ = (char*)ldsB[bi];
      async16(Xb + gb0 + kb, lb_ + tid*16);
      async16(Xb + gb1 + kb, lb_ + (tid+256)*16);
    }
  };
  auto cmp = [&](int bi) {
    compute_step(ldsA[bi], DIAG ? ldsA[bi] : ldsB[bi], aoff, boff, swz, acc);
  };

  stg(0, 0); stg(1, 32);
  #pragma unroll 1
  for (int it = 0; it < 10; ++it) {
    stg(2, (3*it + 2) * 32);
    if constexpr (DIAG) { VMWAIT(4); } else { VMWAIT(8); }
    BAR(); FENCE();
    cmp(0);
    FENCE(); BAR();
    stg(0, (3*it + 3) * 32);
    if constexpr (DIAG) { VMWAIT(4); } else { VMWAIT(8); }
    BAR(); FENCE();
    cmp(1);
    FENCE(); BAR();
    stg(1, (3*it + 4) * 32);
    if constexpr (DIAG) { VMWAIT(4); } else { VMWAIT(8); }
    BAR(); FENCE();
    cmp(2);
    FENCE(); BAR();
  }
  if constexpr (DIAG) { VMWAIT(2); } else { VMWAIT(4); }
  BAR(); FENCE();
  cmp(0);
  FENCE(); BAR();
  VMWAIT(0);
  BAR(); FENCE();
  cmp(1);
}

__global__ __launch_bounds__(256, 3) void k_gram(
    const short* __restrict__ XbT, const float* __restrict__ amu,
    const float* __restrict__ invd, float* __restrict__ out)
{
  __shared__ __align__(16) short ldsA[3][4096];
  __shared__ __align__(16) short ldsB[3][4096];

  const int bid = (blockIdx.x & 7) * 80 + (blockIdx.x >> 3);
  const int b = bid / 10;
  const int t = bid - b * 10;
  const int ip = (t >= 4) + (t >= 7) + (t >= 9);
  const int jp = ip + t - ((ip * (9 - ip)) >> 1);
  const int rowBase = ip * 128, colBase = jp * 128;
  const bool diag = (ip == jp);

  const int tid = threadIdx.x, lane = tid & 63, wave = tid >> 6;
  const int wr = wave >> 1, wc = wave & 1;
  const short* Xb = XbT + (size_t)b * N_ * T_;

  const int r0 = tid >> 2, cl = tid & 3;
  const int cg = cl ^ ((r0 >> 1) & 3);
  const size_t gb0 = (size_t)(colBase + r0)      * T_ + cg * 8;
  const size_t gb1 = (size_t)(colBase + r0 + 64) * T_ + cg * 8;
  const size_t ga0 = (size_t)(rowBase + r0)      * T_ + cg * 8;
  const size_t ga1 = (size_t)(rowBase + r0 + 64) * T_ + cg * 8;

  const int fr = lane & 15, kc = lane >> 4;
  const int swz  = (kc ^ ((fr >> 1) & 3)) * 8;
  const int aoff = (wr * 64 + fr) * 32;
  const int boff = (wc * 64 + fr) * 32;

  f32x4 acc[4][4] = {};
  if (diag) gram_main<true >(Xb, ga0, ga1, gb0, gb1, ldsA, ldsB, tid, aoff, boff, swz, acc);
  else      gram_main<false>(Xb, ga0, ga1, gb0, gb1, ldsA, ldsB, tid, aoff, boff, swz, acc);

  const int jc = colBase + wc * 64 + fr;
  float aj[4], dj[4];
  #pragma unroll
  for (int ni = 0; ni < 4; ++ni) {
    aj[ni] = amu [b*N_ + jc + ni*16];
    dj[ni] = invd[b*N_ + jc + ni*16];
  }
  #pragma unroll
  for (int mi = 0; mi < 4; ++mi) {
    const int ibase = rowBase + wr*64 + mi*16 + kc*4;
    float ai[4], di[4];
    #pragma unroll
    for (int r = 0; r < 4; ++r) {
      ai[r] = amu [b*N_ + ibase + r];
      di[r] = invd[b*N_ + ibase + r];
    }
    #pragma unroll
    for (int ni = 0; ni < 4; ++ni) {
      f32x4 g;
      #pragma unroll
      for (int r = 0; r < 4; ++r) {
        float v = (acc[mi][ni][r] - ai[r]*aj[ni]) * (di[r]*dj[ni]);
        g[r] = fminf(fmaxf(v, -1.f), 1.f);
      }
      const int J = jc + ni * 16;
      #pragma unroll
      for (int r = 0; r < 4; ++r)
        out[((size_t)b*N_ + ibase + r)*N_ + J] = g[r];
      if (!diag)
        *(f32x4*)&out[((size_t)b*N_ + J)*N_ + ibase] = g;
    }
  }
}

extern "C" void kernel_launch(void* const* d_in, const int* in_sizes, int n_in,
                              void* d_out, int out_size, void* d_ws, size_t ws_size,
                              hipStream_t stream) {
  const float* X = (const float*)d_in[0];
  // bn_weight / bn_bias provably cancel in the correlation output.
  float* out = (float*)d_out;

  char* ws = (char*)d_ws;
  short* XbT  = (short*)ws;                      // 64 MiB bf16 (N,T)
  size_t off  = (size_t)B_ * N_ * T_ * sizeof(short);
  float* amu  = (float*)(ws + off);              // 128 KiB
  float* invd = amu + B_ * N_;                   // 128 KiB

  k_prep<<<dim3(16, 64), 256, 0, stream>>>(X, XbT, amu, invd);
  k_gram<<<dim3(64 * 10), 256, 0, stream>>>(XbT, amu, invd, out);
}